// Round 2
// baseline (588.356 us; speedup 1.0000x reference)
//
#include <hip/hip_runtime.h>
#include <math.h>

typedef __bf16 bf16;
typedef __bf16 bf16x4 __attribute__((ext_vector_type(4)));
typedef __bf16 bf16x8 __attribute__((ext_vector_type(8)));
typedef float floatx4 __attribute__((ext_vector_type(4)));

#define MFMA16(a, b, c) __builtin_amdgcn_mfma_f32_16x16x32_bf16(a, b, c, 0, 0, 0)

#if __has_builtin(__builtin_amdgcn_exp2f)
#define EXP2F(x) __builtin_amdgcn_exp2f(x)
#else
#define EXP2F(x) exp2f(x)
#endif

constexpr int Bc = 4, SQc = 2048, SKVc = 2048, Hc = 16, Dc = 64;
// fold 1/sqrt(D) * log2(e) into qh so softmax is exp2 with no extra mul
#define QSCALE 0.18033688011112042f

// ---------------------------------------------------------------------------
// Prepass: fp32 -> bf16 convert (n multiple of 1024, grid = n/1024)
// ---------------------------------------------------------------------------
__global__ void cvt_bf16(const float* __restrict__ in, bf16* __restrict__ out) {
  const size_t i = ((size_t)blockIdx.x * 256 + threadIdx.x) * 4;
  const float4 v = *(const float4*)&in[i];
  bf16x4 o = {(bf16)v.x, (bf16)v.y, (bf16)v.z, (bf16)v.w};
  *(bf16x4*)&out[i] = o;
}

// ---------------------------------------------------------------------------
// Prepass: W [K][N] fp32 -> WT [N][K] bf16. grid (N/64, K/64), 256 thr.
// ---------------------------------------------------------------------------
__global__ void transpose_cvt(const float* __restrict__ in, bf16* __restrict__ out,
                              int K, int N) {
  __shared__ bf16 T[64][72];
  const int tid = threadIdx.x;
  const int n0 = blockIdx.x * 64, k0 = blockIdx.y * 64;
  const int tr = tid >> 4, tc4 = (tid & 15) * 4;
#pragma unroll
  for (int i = 0; i < 4; i++) {
    const int k = tr + 16 * i;
    const float4 v = *(const float4*)&in[(size_t)(k0 + k) * N + n0 + tc4];
    T[tc4 + 0][k] = (bf16)v.x;
    T[tc4 + 1][k] = (bf16)v.y;
    T[tc4 + 2][k] = (bf16)v.z;
    T[tc4 + 3][k] = (bf16)v.w;
  }
  __syncthreads();
  const int nr = tid >> 2, kc = (tid & 3) * 8;
#pragma unroll
  for (int hf = 0; hf < 2; hf++)
    *(bf16x8*)&out[(size_t)(n0 + nr) * K + k0 + kc + 32 * hf] =
        *(const bf16x8*)&T[nr][kc + 32 * hf];
}

// ---------------------------------------------------------------------------
// 128x128-tile bf16 GEMM: C = A[M][K] @ WT[N][K]^T + bias.
//   MODE 0: fp32 out [M][N]
//   MODE 1: RoPE + *QSCALE -> qh bf16 [b][h][s][d]
//   MODE 2: cols<64 RoPE -> k bf16 [b][skv][d]; cols>=64 -> vT bf16 [b][d][skv]
// ---------------------------------------------------------------------------
template <int MODE>
__global__ __launch_bounds__(256) void gemm_bf16(
    const bf16* __restrict__ A, const bf16* __restrict__ BT,
    const float* __restrict__ bias, void* __restrict__ out0,
    void* __restrict__ out1, int M, int K, int N) {
  __shared__ bf16 As[128][40];
  __shared__ bf16 Bs[128][40];

  const int tid = threadIdx.x, lane = tid & 63, wave = tid >> 6;
  const int m = lane & 15, g = lane >> 4;
  const int m0 = blockIdx.x * 128, n0 = blockIdx.y * 128;
  const int mq = (wave >> 1) * 64, nq = (wave & 1) * 64;

  floatx4 z = {0.f, 0.f, 0.f, 0.f};
  floatx4 acc[4][4];
#pragma unroll
  for (int i = 0; i < 4; i++)
#pragma unroll
    for (int j = 0; j < 4; j++) acc[i][j] = z;

  const int srow = tid >> 2, sc8 = (tid & 3) * 8;
  for (int k0 = 0; k0 < K; k0 += 32) {
    __syncthreads();
    *(bf16x8*)&As[srow][sc8] = *(const bf16x8*)&A[(size_t)(m0 + srow) * K + k0 + sc8];
    *(bf16x8*)&As[srow + 64][sc8] =
        *(const bf16x8*)&A[(size_t)(m0 + srow + 64) * K + k0 + sc8];
    *(bf16x8*)&Bs[srow][sc8] = *(const bf16x8*)&BT[(size_t)(n0 + srow) * K + k0 + sc8];
    *(bf16x8*)&Bs[srow + 64][sc8] =
        *(const bf16x8*)&BT[(size_t)(n0 + srow + 64) * K + k0 + sc8];
    __syncthreads();
    bf16x8 a[4], bb[4];
#pragma unroll
    for (int i = 0; i < 4; i++) a[i] = *(const bf16x8*)&As[mq + 16 * i + m][8 * g];
#pragma unroll
    for (int j = 0; j < 4; j++) bb[j] = *(const bf16x8*)&Bs[nq + 16 * j + m][8 * g];
#pragma unroll
    for (int i = 0; i < 4; i++)
#pragma unroll
      for (int j = 0; j < 4; j++) acc[i][j] = MFMA16(a[i], bb[j], acc[i][j]);
  }

  // epilogue: C/D layout col = lane&15 (+16j), row = 4*(lane>>4)+r (+16i)
  const int rq = 4 * g;
#pragma unroll
  for (int j = 0; j < 4; j++) {
    const int col = n0 + nq + 16 * j + m;
    const float bv = bias[col];
#pragma unroll
    for (int i = 0; i < 4; i++) {
#pragma unroll
      for (int r = 0; r < 4; r++) {
        const int row = m0 + mq + 16 * i + rq + r;
        float v = acc[i][j][r] + bv;
        if constexpr (MODE == 0) {
          ((float*)out0)[(size_t)row * N + col] = v;
        } else if constexpr (MODE == 1) {
          const float vp = __shfl_xor(v, 1);
          const int d = col & 63, hh = col >> 6;
          const int pos = row & (SQc - 1), b = row >> 11;
          const float ang = (float)pos * exp2f(-0.375f * (float)(d >> 1));
          float sn, cs;
          sincosf(ang, &sn, &cs);
          const float res = (d & 1) ? (v * cs + vp * sn) : (v * cs - vp * sn);
          ((bf16*)out0)[(((size_t)(b * Hc + hh) * SQc) + pos) * Dc + d] =
              (bf16)(res * QSCALE);
        } else {  // MODE 2
          const float vp = __shfl_xor(v, 1);
          const int pos = row & (SKVc - 1), b = row >> 11;
          if (col < 64) {
            const int d = col;
            const float ang = (float)pos * exp2f(-0.375f * (float)(d >> 1));
            float sn, cs;
            sincosf(ang, &sn, &cs);
            const float res = (d & 1) ? (v * cs + vp * sn) : (v * cs - vp * sn);
            ((bf16*)out0)[((size_t)b * SKVc + pos) * Dc + d] = (bf16)res;
          } else {
            ((bf16*)out1)[((size_t)b * Dc + (col - 64)) * SKVc + pos] = (bf16)v;
          }
        }
      }
    }
  }
}

// ---------------------------------------------------------------------------
// Flash attention v2: S^T trick, no-max exp2 softmax, per-wave P relayout
// (no barrier), K double-buffered in LDS (1 barrier/iter), V direct from L2.
// Block = 128 q-rows (4 waves x 32). Grid = B*H*(SQ/128) = 1024.
// ---------------------------------------------------------------------------
__global__ __launch_bounds__(256) void attn_v2(
    const bf16* __restrict__ qh, const bf16* __restrict__ kk,
    const bf16* __restrict__ vt, bf16* __restrict__ hout) {
  const int bid = blockIdx.x;
  const int qt = bid & 15, h = (bid >> 4) & 15, b = bid >> 8;
  const int tid = threadIdx.x, lane = tid & 63, wave = tid >> 6;
  const int m = lane & 15, g = lane >> 4;

  __shared__ bf16 Ks[2][64][72];
  __shared__ bf16 Pb[4][32][72];

  const int q0 = qt * 128 + wave * 32;
  // Q fragments (B-operand: n=q in lane&15, k=d)
  const bf16* qp = qh + (((size_t)(b * Hc + h) * SQc) + q0 + m) * Dc + 8 * g;
  bf16x8 bq[2][2];
  bq[0][0] = *(const bf16x8*)qp;
  bq[0][1] = *(const bf16x8*)(qp + 32);
  bq[1][0] = *(const bf16x8*)(qp + 16 * Dc);
  bq[1][1] = *(const bf16x8*)(qp + 16 * Dc + 32);

  floatx4 z = {0.f, 0.f, 0.f, 0.f};
  floatx4 accO[2][4];
#pragma unroll
  for (int s = 0; s < 2; s++)
#pragma unroll
    for (int t = 0; t < 4; t++) accO[s][t] = z;
  float lsum[2] = {0.f, 0.f};

  const bf16* kbase = kk + (size_t)b * SKVc * Dc;
  const bf16* vbase = vt + ((size_t)b * Dc + m) * SKVc + 8 * g;
  const int krow = tid >> 2, kc = (tid & 3) * 8;

  bf16x8 kst0, kst1;
  {
    const bf16* p = kbase + (size_t)krow * Dc + kc;
    kst0 = *(const bf16x8*)p;
    kst1 = *(const bf16x8*)(p + 32);
    bf16* d = &Ks[0][krow][kc];
    *(bf16x8*)d = kst0;
    *(bf16x8*)(d + 32) = kst1;
    const bf16* p2 = kbase + (size_t)(64 + krow) * Dc + kc;
    kst0 = *(const bf16x8*)p2;
    kst1 = *(const bf16x8*)(p2 + 32);
  }

  for (int it = 0; it < 32; ++it) {
    __syncthreads();
    if (it + 1 < 32) {
      bf16* d = &Ks[(it + 1) & 1][krow][kc];
      *(bf16x8*)d = kst0;
      *(bf16x8*)(d + 32) = kst1;
      if (it + 2 < 32) {
        const bf16* p = kbase + (size_t)((it + 2) * 64 + krow) * Dc + kc;
        kst0 = *(const bf16x8*)p;
        kst1 = *(const bf16x8*)(p + 32);
      }
    }
    const int cb = it & 1;
    // ---- S^T = K Q^T: D[key][q], 16 MFMAs ----
    floatx4 sT[2][4];
#pragma unroll
    for (int c = 0; c < 4; c++) {
      const bf16x8 ka0 = *(const bf16x8*)&Ks[cb][16 * c + m][8 * g];
      const bf16x8 ka1 = *(const bf16x8*)&Ks[cb][16 * c + m][32 + 8 * g];
#pragma unroll
      for (int s = 0; s < 2; s++) {
        sT[s][c] = MFMA16(ka0, bq[s][0], z);
        sT[s][c] = MFMA16(ka1, bq[s][1], sT[s][c]);
      }
    }
    // ---- p = exp2(s); partial row-sums; pack into per-wave Pb (no barrier) --
#pragma unroll
    for (int s = 0; s < 2; s++)
#pragma unroll
      for (int c = 0; c < 4; c++) {
        const float e0 = EXP2F(sT[s][c][0]);
        const float e1 = EXP2F(sT[s][c][1]);
        const float e2 = EXP2F(sT[s][c][2]);
        const float e3 = EXP2F(sT[s][c][3]);
        lsum[s] += (e0 + e1) + (e2 + e3);
        bf16x4 pk = {(bf16)e0, (bf16)e1, (bf16)e2, (bf16)e3};
        *(bf16x4*)&Pb[wave][16 * s + m][16 * c + 4 * g] = pk;
      }
    bf16x8 pa[2][2];
#pragma unroll
    for (int s = 0; s < 2; s++) {
      pa[s][0] = *(const bf16x8*)&Pb[wave][16 * s + m][8 * g];
      pa[s][1] = *(const bf16x8*)&Pb[wave][16 * s + m][32 + 8 * g];
    }
    // ---- O += P V : V B-operand direct from global (L1/L2 resident) ----
    const int kt = it * 64;
#pragma unroll
    for (int t = 0; t < 4; t++) {
      const bf16* vp = vbase + (size_t)(16 * t) * SKVc + kt;
      const bf16x8 bv0 = *(const bf16x8*)vp;
      const bf16x8 bv1 = *(const bf16x8*)(vp + 32);
#pragma unroll
      for (int s = 0; s < 2; s++) {
        accO[s][t] = MFMA16(pa[s][0], bv0, accO[s][t]);
        accO[s][t] = MFMA16(pa[s][1], bv1, accO[s][t]);
      }
    }
  }

  // ---- final: reduce l across lane groups, normalize, store ----
  float inv[2][4];
#pragma unroll
  for (int s = 0; s < 2; s++) {
    float tt = lsum[s];
    tt += __shfl_xor(tt, 16);
    tt += __shfl_xor(tt, 32);
#pragma unroll
    for (int r = 0; r < 4; r++) inv[s][r] = 1.0f / __shfl(tt, 4 * g + r);
  }
#pragma unroll
  for (int s = 0; s < 2; s++)
#pragma unroll
    for (int t = 0; t < 4; t++)
#pragma unroll
      for (int r = 0; r < 4; r++) {
        const int qrow = q0 + 16 * s + 4 * g + r;
        hout[((size_t)(b * SQc + qrow)) * (Hc * Dc) + h * Dc + 16 * t + m] =
            (bf16)(accO[s][t][r] * inv[s][r]);
      }
}

// ---------------------------------------------------------------------------
extern "C" void kernel_launch(void* const* d_in, const int* in_sizes, int n_in,
                              void* d_out, int out_size, void* d_ws, size_t ws_size,
                              hipStream_t stream) {
  const float* q = (const float*)d_in[0];
  const float* kv = (const float*)d_in[1];
  const float* Wq = (const float*)d_in[2];
  const float* bq = (const float*)d_in[3];
  const float* Wkv = (const float*)d_in[4];
  const float* bkv = (const float*)d_in[5];
  const float* Wo = (const float*)d_in[6];
  const float* bo = (const float*)d_in[7];

  char* ws = (char*)d_ws;
  bf16* qbf = (bf16*)ws;                            // 16 MiB (reused as hh later)
  bf16* kvbf = (bf16*)(ws + ((size_t)16 << 20));    // 16 MiB
  bf16* WqT = (bf16*)(ws + ((size_t)32 << 20));     // 2 MiB
  bf16* WkvT = (bf16*)(ws + ((size_t)34 << 20));    // 256 KiB
  bf16* WoT = (bf16*)(ws + ((size_t)35 << 20));     // 2 MiB
  bf16* qh = (bf16*)(ws + ((size_t)37 << 20));      // 16 MiB
  bf16* kk = (bf16*)(ws + ((size_t)53 << 20));      // 1 MiB
  bf16* vt = (bf16*)(ws + ((size_t)54 << 20));      // 1 MiB
  bf16* hh = qbf;  // alias: qbf dead after gemm1, hh written by attn

  const int M = Bc * SQc;  // 8192

  cvt_bf16<<<M * 1024 / 1024, 256, 0, stream>>>(q, qbf);
  cvt_bf16<<<M * 1024 / 1024, 256, 0, stream>>>(kv, kvbf);
  transpose_cvt<<<dim3(16, 16), 256, 0, stream>>>(Wq, WqT, 1024, 1024);
  transpose_cvt<<<dim3(2, 16), 256, 0, stream>>>(Wkv, WkvT, 1024, 128);
  transpose_cvt<<<dim3(16, 16), 256, 0, stream>>>(Wo, WoT, 1024, 1024);

  gemm_bf16<1><<<dim3(64, 8), 256, 0, stream>>>(qbf, WqT, bq, (void*)qh, nullptr,
                                                M, 1024, 1024);
  gemm_bf16<2><<<dim3(64, 1), 256, 0, stream>>>(kvbf, WkvT, bkv, (void*)kk,
                                                (void*)vt, M, 1024, 128);
  attn_v2<<<Bc * Hc * (SQc / 128), 256, 0, stream>>>(qh, kk, vt, hh);
  gemm_bf16<0><<<dim3(64, 8), 256, 0, stream>>>(hh, WoT, bo, d_out, nullptr, M,
                                                1024, 1024);
}

// Round 3
// 544.197 us; speedup vs baseline: 1.0811x; 1.0811x over previous
//
#include <hip/hip_runtime.h>
#include <math.h>

typedef __bf16 bf16;
typedef __bf16 bf16x4 __attribute__((ext_vector_type(4)));
typedef __bf16 bf16x8 __attribute__((ext_vector_type(8)));
typedef float floatx4 __attribute__((ext_vector_type(4)));

#define MFMA16(a, b, c) __builtin_amdgcn_mfma_f32_16x16x32_bf16(a, b, c, 0, 0, 0)

#if __has_builtin(__builtin_amdgcn_exp2f)
#define EXP2F(x) __builtin_amdgcn_exp2f(x)
#else
#define EXP2F(x) exp2f(x)
#endif

constexpr int Bc = 4, SQc = 2048, SKVc = 2048, Hc = 16, Dc = 64;
// fold 1/sqrt(D) * log2(e) into qh so softmax is exp2 with no extra mul
#define QSCALE 0.18033688011112042f

// Async global->LDS, 16B per lane. LDS dest is wave-uniform base + lane*16.
__device__ __forceinline__ void glds16(const bf16* g, bf16* lds_base, int lane) {
#if __has_builtin(__builtin_amdgcn_global_load_lds)
  __builtin_amdgcn_global_load_lds(
      (const __attribute__((address_space(1))) void*)g,
      (__attribute__((address_space(3))) void*)lds_base, 16, 0, 0);
#else
  *(bf16x8*)(lds_base + 8 * lane) = *(const bf16x8*)g;
#endif
}

// ---------------------------------------------------------------------------
// Prepass: fp32 -> bf16 convert (1024 elems per block)
// ---------------------------------------------------------------------------
__global__ void cvt_bf16(const float* __restrict__ in, bf16* __restrict__ out) {
  const size_t i = ((size_t)blockIdx.x * 256 + threadIdx.x) * 4;
  const float4 v = *(const float4*)&in[i];
  bf16x4 o = {(bf16)v.x, (bf16)v.y, (bf16)v.z, (bf16)v.w};
  *(bf16x4*)&out[i] = o;
}

// ---------------------------------------------------------------------------
// Prepass: W [K][N] fp32 -> WT [N][K] bf16. grid (N/64, K/64), 256 thr.
// ---------------------------------------------------------------------------
__global__ void transpose_cvt(const float* __restrict__ in, bf16* __restrict__ out,
                              int K, int N) {
  __shared__ bf16 T[64][72];
  const int tid = threadIdx.x;
  const int n0 = blockIdx.x * 64, k0 = blockIdx.y * 64;
  const int tr = tid >> 4, tc4 = (tid & 15) * 4;
#pragma unroll
  for (int i = 0; i < 4; i++) {
    const int k = tr + 16 * i;
    const float4 v = *(const float4*)&in[(size_t)(k0 + k) * N + n0 + tc4];
    T[tc4 + 0][k] = (bf16)v.x;
    T[tc4 + 1][k] = (bf16)v.y;
    T[tc4 + 2][k] = (bf16)v.z;
    T[tc4 + 3][k] = (bf16)v.w;
  }
  __syncthreads();
  const int nr = tid >> 2, kc = (tid & 3) * 8;
#pragma unroll
  for (int hf = 0; hf < 2; hf++)
    *(bf16x8*)&out[(size_t)(n0 + nr) * K + k0 + kc + 32 * hf] =
        *(const bf16x8*)&T[nr][kc + 32 * hf];
}

// ---------------------------------------------------------------------------
// 128x128-tile bf16 GEMM, BK=64, global_load_lds(16B) staging with XOR-swizzled
// 16B granules (physical granule p holds source granule p^(row&7)); fragment
// ds_read_b128 is then bank-conflict-free (2 lanes/bank).
//   MODE 0: fp32 out [M][N]
//   MODE 1: RoPE + *QSCALE -> qh bf16 [b][h][s][d]
//   MODE 2: cols<64 RoPE -> k bf16 [b][skv][d]; cols>=64 -> vT bf16 [b][d][skv]
// ---------------------------------------------------------------------------
template <int MODE>
__global__ __launch_bounds__(256, 3) void gemm_bf16(
    const bf16* __restrict__ A, const bf16* __restrict__ BT,
    const float* __restrict__ bias, void* __restrict__ out0,
    void* __restrict__ out1, int M, int K, int N) {
  __shared__ bf16 As[128 * 64];
  __shared__ bf16 Bs[128 * 64];

  const int tid = threadIdx.x, lane = tid & 63, wave = tid >> 6;
  const int m = lane & 15, g = lane >> 4;
  const int m0 = blockIdx.x * 128, n0 = blockIdx.y * 128;
  const int mq = (wave >> 1) * 64, nq = (wave & 1) * 64;

  floatx4 z = {0.f, 0.f, 0.f, 0.f};
  floatx4 acc[4][4];
#pragma unroll
  for (int i = 0; i < 4; i++)
#pragma unroll
    for (int j = 0; j < 4; j++) acc[i][j] = z;

  for (int k0 = 0; k0 < K; k0 += 64) {
    __syncthreads();
#pragma unroll
    for (int q = 0; q < 4; q++) {
      const int G = q * 256 + tid;          // granule index 0..1023
      const int r = G >> 3, p = G & 7;      // row, physical granule
      const int s = p ^ (r & 7);            // source granule (swizzle)
      bf16* base = &As[(size_t)(q * 4 + wave) * 512];  // wave-uniform
      glds16(&A[(size_t)(m0 + r) * K + k0 + 8 * s], base, lane);
      bf16* baseB = &Bs[(size_t)(q * 4 + wave) * 512];
      glds16(&BT[(size_t)(n0 + r) * K + k0 + 8 * s], baseB, lane);
    }
    __syncthreads();  // drains vmcnt -> LDS tiles visible

    bf16x8 a[4][2], bb[4][2];
#pragma unroll
    for (int i = 0; i < 4; i++) {
      const int row = mq + 16 * i + m;
#pragma unroll
      for (int kh = 0; kh < 2; kh++)
        a[i][kh] = *(const bf16x8*)&As[row * 64 + 8 * ((g + 4 * kh) ^ (row & 7))];
    }
#pragma unroll
    for (int j = 0; j < 4; j++) {
      const int row = nq + 16 * j + m;
#pragma unroll
      for (int kh = 0; kh < 2; kh++)
        bb[j][kh] = *(const bf16x8*)&Bs[row * 64 + 8 * ((g + 4 * kh) ^ (row & 7))];
    }
#pragma unroll
    for (int i = 0; i < 4; i++)
#pragma unroll
      for (int j = 0; j < 4; j++) {
        acc[i][j] = MFMA16(a[i][0], bb[j][0], acc[i][j]);
        acc[i][j] = MFMA16(a[i][1], bb[j][1], acc[i][j]);
      }
  }

  // epilogue: C/D layout col = lane&15 (+16j), row = 4*(lane>>4)+r (+16i)
  const int rq = 4 * g;
#pragma unroll
  for (int j = 0; j < 4; j++) {
    const int col = n0 + nq + 16 * j + m;
    const float bv = bias[col];
#pragma unroll
    for (int i = 0; i < 4; i++) {
#pragma unroll
      for (int r = 0; r < 4; r++) {
        const int row = m0 + mq + 16 * i + rq + r;
        float v = acc[i][j][r] + bv;
        if constexpr (MODE == 0) {
          ((float*)out0)[(size_t)row * N + col] = v;
        } else if constexpr (MODE == 1) {
          const float vp = __shfl_xor(v, 1);
          const int d = col & 63, hh = col >> 6;
          const int pos = row & (SQc - 1), b = row >> 11;
          const float ang = (float)pos * exp2f(-0.375f * (float)(d >> 1));
          float sn, cs;
          sincosf(ang, &sn, &cs);
          const float res = (d & 1) ? (v * cs + vp * sn) : (v * cs - vp * sn);
          ((bf16*)out0)[(((size_t)(b * Hc + hh) * SQc) + pos) * Dc + d] =
              (bf16)(res * QSCALE);
        } else {  // MODE 2
          const float vp = __shfl_xor(v, 1);
          const int pos = row & (SKVc - 1), b = row >> 11;
          if (col < 64) {  // wave-uniform (nq is 0 or 64)
            const int d = col;
            const float ang = (float)pos * exp2f(-0.375f * (float)(d >> 1));
            float sn, cs;
            sincosf(ang, &sn, &cs);
            const float res = (d & 1) ? (v * cs + vp * sn) : (v * cs - vp * sn);
            ((bf16*)out0)[((size_t)b * SKVc + pos) * Dc + d] = (bf16)res;
          } else {
            ((bf16*)out1)[((size_t)b * Dc + (col - 64)) * SKVc + pos] = (bf16)v;
          }
        }
      }
    }
  }
}

// ---------------------------------------------------------------------------
// Flash attention v3: barrier-free. K and V fragments read directly from
// global (L1-resident, 8KB tiles shared by the block's 4 waves). Per-wave LDS
// only for the P C-layout -> A-layout relayout. Row-sums computed by an extra
// MFMA against a ones vector (lands register-aligned with accO -> no shuffles).
// Block = 128 q-rows (4 waves x 32). Grid = B*H*(SQ/128) = 1024.
// ---------------------------------------------------------------------------
__global__ __launch_bounds__(256, 3) void attn_v3(
    const bf16* __restrict__ qh, const bf16* __restrict__ kk,
    const bf16* __restrict__ vt, bf16* __restrict__ hout) {
  const int bid = blockIdx.x;
  const int qt = bid & 15, h = (bid >> 4) & 15, b = bid >> 8;
  const int tid = threadIdx.x, lane = tid & 63, wave = tid >> 6;
  const int m = lane & 15, g = lane >> 4;

  __shared__ bf16 Pb[4][32][68];  // per-wave P relayout; pad 68 -> ~free banks

  const int q0 = qt * 128 + wave * 32;
  // Q fragments (B-operand: n=q in lane&15, k=d)
  const bf16* qp = qh + (((size_t)(b * Hc + h) * SQc) + q0 + m) * Dc + 8 * g;
  bf16x8 bq[2][2];
  bq[0][0] = *(const bf16x8*)qp;
  bq[0][1] = *(const bf16x8*)(qp + 32);
  bq[1][0] = *(const bf16x8*)(qp + 16 * Dc);
  bq[1][1] = *(const bf16x8*)(qp + 16 * Dc + 32);

  const bf16 one = (bf16)1.0f;
  const bf16x8 ones = {one, one, one, one, one, one, one, one};

  floatx4 z = {0.f, 0.f, 0.f, 0.f};
  floatx4 accO[2][4];
  floatx4 lacc[2] = {z, z};
#pragma unroll
  for (int s = 0; s < 2; s++)
#pragma unroll
    for (int t = 0; t < 4; t++) accO[s][t] = z;

  const bf16* kb = kk + (size_t)b * SKVc * Dc;
  const bf16* vb = vt + ((size_t)b * Dc + m) * SKVc + 8 * g;

  for (int it = 0; it < 32; ++it) {
    const int kt = it * 64;
    // ---- S^T = K Q^T, exp2, pack to per-wave Pb (no barrier needed) ----
#pragma unroll
    for (int c = 0; c < 4; c++) {
      const bf16* kp = kb + (size_t)(kt + 16 * c + m) * Dc + 8 * g;
      const bf16x8 ka0 = *(const bf16x8*)kp;
      const bf16x8 ka1 = *(const bf16x8*)(kp + 32);
#pragma unroll
      for (int s = 0; s < 2; s++) {
        floatx4 sv = MFMA16(ka0, bq[s][0], z);
        sv = MFMA16(ka1, bq[s][1], sv);
        bf16x4 pk = {(bf16)EXP2F(sv[0]), (bf16)EXP2F(sv[1]), (bf16)EXP2F(sv[2]),
                     (bf16)EXP2F(sv[3])};
        *(bf16x4*)&Pb[wave][16 * s + m][16 * c + 4 * g] = pk;
      }
    }
    bf16x8 pa[2][2];
#pragma unroll
    for (int s = 0; s < 2; s++) {
      pa[s][0] = *(const bf16x8*)&Pb[wave][16 * s + m][8 * g];
      pa[s][1] = *(const bf16x8*)&Pb[wave][16 * s + m][32 + 8 * g];
    }
    // ---- row-sums via MFMA against ones (aligned with accO layout) ----
#pragma unroll
    for (int s = 0; s < 2; s++) {
      lacc[s] = MFMA16(pa[s][0], ones, lacc[s]);
      lacc[s] = MFMA16(pa[s][1], ones, lacc[s]);
    }
    // ---- O += P V : V B-operand direct from global (L1-resident) ----
#pragma unroll
    for (int t = 0; t < 4; t++) {
      const bf16* vp = vb + (size_t)(16 * t) * SKVc + kt;
      const bf16x8 bv0 = *(const bf16x8*)vp;
      const bf16x8 bv1 = *(const bf16x8*)(vp + 32);
#pragma unroll
      for (int s = 0; s < 2; s++) {
        accO[s][t] = MFMA16(pa[s][0], bv0, accO[s][t]);
        accO[s][t] = MFMA16(pa[s][1], bv1, accO[s][t]);
      }
    }
  }

  // ---- normalize and store h[b][s][h*64+d] ----
#pragma unroll
  for (int s = 0; s < 2; s++) {
    floatx4 inv;
#pragma unroll
    for (int r = 0; r < 4; r++) inv[r] = 1.0f / lacc[s][r];
#pragma unroll
    for (int t = 0; t < 4; t++)
#pragma unroll
      for (int r = 0; r < 4; r++) {
        const int qrow = q0 + 16 * s + 4 * g + r;
        hout[((size_t)(b * SQc + qrow)) * (Hc * Dc) + h * Dc + 16 * t + m] =
            (bf16)(accO[s][t][r] * inv[r]);
      }
  }
}

// ---------------------------------------------------------------------------
extern "C" void kernel_launch(void* const* d_in, const int* in_sizes, int n_in,
                              void* d_out, int out_size, void* d_ws, size_t ws_size,
                              hipStream_t stream) {
  const float* q = (const float*)d_in[0];
  const float* kv = (const float*)d_in[1];
  const float* Wq = (const float*)d_in[2];
  const float* bq = (const float*)d_in[3];
  const float* Wkv = (const float*)d_in[4];
  const float* bkv = (const float*)d_in[5];
  const float* Wo = (const float*)d_in[6];
  const float* bo = (const float*)d_in[7];

  char* ws = (char*)d_ws;
  bf16* qbf = (bf16*)ws;                            // 16 MiB (reused as hh later)
  bf16* kvbf = (bf16*)(ws + ((size_t)16 << 20));    // 16 MiB
  bf16* WqT = (bf16*)(ws + ((size_t)32 << 20));     // 2 MiB
  bf16* WkvT = (bf16*)(ws + ((size_t)34 << 20));    // 256 KiB
  bf16* WoT = (bf16*)(ws + ((size_t)35 << 20));     // 2 MiB
  bf16* qh = (bf16*)(ws + ((size_t)37 << 20));      // 16 MiB
  bf16* kk = (bf16*)(ws + ((size_t)53 << 20));      // 1 MiB
  bf16* vt = (bf16*)(ws + ((size_t)54 << 20));      // 1 MiB
  bf16* hh = qbf;  // alias: qbf dead after gemm1, hh written by attn

  const int M = Bc * SQc;  // 8192

  cvt_bf16<<<M, 256, 0, stream>>>(q, qbf);
  cvt_bf16<<<M, 256, 0, stream>>>(kv, kvbf);
  transpose_cvt<<<dim3(16, 16), 256, 0, stream>>>(Wq, WqT, 1024, 1024);
  transpose_cvt<<<dim3(2, 16), 256, 0, stream>>>(Wkv, WkvT, 1024, 128);
  transpose_cvt<<<dim3(16, 16), 256, 0, stream>>>(Wo, WoT, 1024, 1024);

  gemm_bf16<1><<<dim3(64, 8), 256, 0, stream>>>(qbf, WqT, bq, (void*)qh, nullptr,
                                                M, 1024, 1024);
  gemm_bf16<2><<<dim3(64, 1), 256, 0, stream>>>(kvbf, WkvT, bkv, (void*)kk,
                                                (void*)vt, M, 1024, 128);
  attn_v3<<<Bc * Hc * (SQc / 128), 256, 0, stream>>>(qh, kk, vt, hh);
  gemm_bf16<0><<<dim3(64, 8), 256, 0, stream>>>(hh, WoT, bo, d_out, nullptr, M,
                                                1024, 1024);
}

// Round 4
// 436.259 us; speedup vs baseline: 1.3486x; 1.2474x over previous
//
#include <hip/hip_runtime.h>
#include <math.h>

typedef __bf16 bf16;
typedef __bf16 bf16x4 __attribute__((ext_vector_type(4)));
typedef __bf16 bf16x8 __attribute__((ext_vector_type(8)));
typedef float floatx4 __attribute__((ext_vector_type(4)));

#define MFMA16(a, b, c) __builtin_amdgcn_mfma_f32_16x16x32_bf16(a, b, c, 0, 0, 0)

#if __has_builtin(__builtin_amdgcn_exp2f)
#define EXP2F(x) __builtin_amdgcn_exp2f(x)
#else
#define EXP2F(x) exp2f(x)
#endif

constexpr int Bc = 4, SQc = 2048, SKVc = 2048, Hc = 16, Dc = 64;
// fold 1/sqrt(D) * log2(e) into qh so softmax is exp2 with no extra mul
#define QSCALE 0.18033688011112042f

// Async global->LDS, 16B per lane. LDS dest is wave-uniform base + lane*16.
__device__ __forceinline__ void glds16(const bf16* g, bf16* lds_base, int lane) {
#if __has_builtin(__builtin_amdgcn_global_load_lds)
  __builtin_amdgcn_global_load_lds(
      (const __attribute__((address_space(1))) void*)g,
      (__attribute__((address_space(3))) void*)lds_base, 16, 0, 0);
#else
  *(bf16x8*)(lds_base + 8 * lane) = *(const bf16x8*)g;
#endif
}

// ---------------------------------------------------------------------------
// Prepass: fp32 -> bf16 convert (1024 elems per block)
// ---------------------------------------------------------------------------
__global__ void cvt_bf16(const float* __restrict__ in, bf16* __restrict__ out) {
  const size_t i = ((size_t)blockIdx.x * 256 + threadIdx.x) * 4;
  const float4 v = *(const float4*)&in[i];
  bf16x4 o = {(bf16)v.x, (bf16)v.y, (bf16)v.z, (bf16)v.w};
  *(bf16x4*)&out[i] = o;
}

// ---------------------------------------------------------------------------
// Prepass: W [K][N] fp32 -> WT [N][K] bf16. grid (N/64, K/64), 256 thr.
// ---------------------------------------------------------------------------
__global__ void transpose_cvt(const float* __restrict__ in, bf16* __restrict__ out,
                              int K, int N) {
  __shared__ bf16 T[64][72];
  const int tid = threadIdx.x;
  const int n0 = blockIdx.x * 64, k0 = blockIdx.y * 64;
  const int tr = tid >> 4, tc4 = (tid & 15) * 4;
#pragma unroll
  for (int i = 0; i < 4; i++) {
    const int k = tr + 16 * i;
    const float4 v = *(const float4*)&in[(size_t)(k0 + k) * N + n0 + tc4];
    T[tc4 + 0][k] = (bf16)v.x;
    T[tc4 + 1][k] = (bf16)v.y;
    T[tc4 + 2][k] = (bf16)v.z;
    T[tc4 + 3][k] = (bf16)v.w;
  }
  __syncthreads();
  const int nr = tid >> 2, kc = (tid & 3) * 8;
#pragma unroll
  for (int hf = 0; hf < 2; hf++)
    *(bf16x8*)&out[(size_t)(n0 + nr) * K + k0 + kc + 32 * hf] =
        *(const bf16x8*)&T[nr][kc + 32 * hf];
}

// ---------------------------------------------------------------------------
// 128x128-tile bf16 GEMM, BK=64, global_load_lds(16B) staging with XOR-swizzled
// 16B granules; fragment ds_read_b128 is bank-conflict-free.
//   MODE 0: fp32 out [M][N]
//   MODE 1: RoPE + *QSCALE -> qh bf16 [b][h][s][d]
//   MODE 2: cols<64 RoPE -> k bf16 [b][skv][d]; cols>=64 -> vT bf16 [b][d][skv]
// ---------------------------------------------------------------------------
template <int MODE>
__global__ __launch_bounds__(256, 3) void gemm_bf16(
    const bf16* __restrict__ A, const bf16* __restrict__ BT,
    const float* __restrict__ bias, void* __restrict__ out0,
    void* __restrict__ out1, int M, int K, int N) {
  __shared__ bf16 As[128 * 64];
  __shared__ bf16 Bs[128 * 64];

  const int tid = threadIdx.x, lane = tid & 63, wave = tid >> 6;
  const int m = lane & 15, g = lane >> 4;
  const int m0 = blockIdx.x * 128, n0 = blockIdx.y * 128;
  const int mq = (wave >> 1) * 64, nq = (wave & 1) * 64;

  floatx4 z = {0.f, 0.f, 0.f, 0.f};
  floatx4 acc[4][4];
#pragma unroll
  for (int i = 0; i < 4; i++)
#pragma unroll
    for (int j = 0; j < 4; j++) acc[i][j] = z;

  for (int k0 = 0; k0 < K; k0 += 64) {
    __syncthreads();
#pragma unroll
    for (int q = 0; q < 4; q++) {
      const int G = q * 256 + tid;          // granule index 0..1023
      const int r = G >> 3, p = G & 7;      // row, physical granule
      const int s = p ^ (r & 7);            // source granule (swizzle)
      bf16* base = &As[(size_t)(q * 4 + wave) * 512];  // wave-uniform
      glds16(&A[(size_t)(m0 + r) * K + k0 + 8 * s], base, lane);
      bf16* baseB = &Bs[(size_t)(q * 4 + wave) * 512];
      glds16(&BT[(size_t)(n0 + r) * K + k0 + 8 * s], baseB, lane);
    }
    __syncthreads();  // drains vmcnt -> LDS tiles visible

    bf16x8 a[4][2], bb[4][2];
#pragma unroll
    for (int i = 0; i < 4; i++) {
      const int row = mq + 16 * i + m;
#pragma unroll
      for (int kh = 0; kh < 2; kh++)
        a[i][kh] = *(const bf16x8*)&As[row * 64 + 8 * ((g + 4 * kh) ^ (row & 7))];
    }
#pragma unroll
    for (int j = 0; j < 4; j++) {
      const int row = nq + 16 * j + m;
#pragma unroll
      for (int kh = 0; kh < 2; kh++)
        bb[j][kh] = *(const bf16x8*)&Bs[row * 64 + 8 * ((g + 4 * kh) ^ (row & 7))];
    }
#pragma unroll
    for (int i = 0; i < 4; i++)
#pragma unroll
      for (int j = 0; j < 4; j++) {
        acc[i][j] = MFMA16(a[i][0], bb[j][0], acc[i][j]);
        acc[i][j] = MFMA16(a[i][1], bb[j][1], acc[i][j]);
      }
  }

  // epilogue: C/D layout col = lane&15 (+16j), row = 4*(lane>>4)+r (+16i)
  const int rq = 4 * g;
#pragma unroll
  for (int j = 0; j < 4; j++) {
    const int col = n0 + nq + 16 * j + m;
    const float bv = bias[col];
#pragma unroll
    for (int i = 0; i < 4; i++) {
#pragma unroll
      for (int r = 0; r < 4; r++) {
        const int row = m0 + mq + 16 * i + rq + r;
        float v = acc[i][j][r] + bv;
        if constexpr (MODE == 0) {
          ((float*)out0)[(size_t)row * N + col] = v;
        } else if constexpr (MODE == 1) {
          const float vp = __shfl_xor(v, 1);
          const int d = col & 63, hh = col >> 6;
          const int pos = row & (SQc - 1), b = row >> 11;
          const float ang = (float)pos * exp2f(-0.375f * (float)(d >> 1));
          float sn, cs;
          sincosf(ang, &sn, &cs);
          const float res = (d & 1) ? (v * cs + vp * sn) : (v * cs - vp * sn);
          ((bf16*)out0)[(((size_t)(b * Hc + hh) * SQc) + pos) * Dc + d] =
              (bf16)(res * QSCALE);
        } else {  // MODE 2
          const float vp = __shfl_xor(v, 1);
          const int pos = row & (SKVc - 1), b = row >> 11;
          if (col < 64) {  // wave-uniform (nq is 0 or 64)
            const int d = col;
            const float ang = (float)pos * exp2f(-0.375f * (float)(d >> 1));
            float sn, cs;
            sincosf(ang, &sn, &cs);
            const float res = (d & 1) ? (v * cs + vp * sn) : (v * cs - vp * sn);
            ((bf16*)out0)[((size_t)b * SKVc + pos) * Dc + d] = (bf16)res;
          } else {
            ((bf16*)out1)[((size_t)b * Dc + (col - 64)) * SKVc + pos] = (bf16)v;
          }
        }
      }
    }
  }
}

// ---------------------------------------------------------------------------
// Flash attention v4: barrier-free, 64 q-rows per wave (4 s-blocks of 16),
// K prefetched one iteration ahead in registers, V loaded at iter top and
// consumed ~300cy later. Row-sums via MFMA against ones. P relayout through
// per-wave LDS (stride-68 layout, measured 0 bank conflicts in v3).
// Block = 256 q-rows (4 waves x 64). Grid = B*H*(SQ/256) = 512; consecutive
// blocks share (b,h) so K/V tiles are L1/L2-resident.
// ---------------------------------------------------------------------------
__global__ __launch_bounds__(256, 2) void attn_v4(
    const bf16* __restrict__ qh, const bf16* __restrict__ kk,
    const bf16* __restrict__ vt, bf16* __restrict__ hout) {
  const int bid = blockIdx.x;
  const int qt = bid & 7, h = (bid >> 3) & 15, b = bid >> 7;
  const int tid = threadIdx.x, lane = tid & 63, wave = tid >> 6;
  const int m = lane & 15, g = lane >> 4;

  __shared__ bf16 Pb[4][16][68];  // per-wave P relayout, reused across s-blocks

  const int q0 = qt * 256 + wave * 64;
  // Q fragments (B-operand: n=q in lane&15, k=d)
  const bf16* qp = qh + (((size_t)(b * Hc + h) * SQc) + q0 + m) * Dc + 8 * g;
  bf16x8 bq[4][2];
#pragma unroll
  for (int s = 0; s < 4; s++) {
    bq[s][0] = *(const bf16x8*)(qp + (size_t)(16 * s) * Dc);
    bq[s][1] = *(const bf16x8*)(qp + (size_t)(16 * s) * Dc + 32);
  }

  const bf16 one = (bf16)1.0f;
  const bf16x8 ones = {one, one, one, one, one, one, one, one};

  floatx4 z = {0.f, 0.f, 0.f, 0.f};
  floatx4 accO[4][4];
  floatx4 lacc[4] = {z, z, z, z};
#pragma unroll
  for (int s = 0; s < 4; s++)
#pragma unroll
    for (int t = 0; t < 4; t++) accO[s][t] = z;

  const bf16* kb = kk + (size_t)b * SKVc * Dc;
  const bf16* vb = vt + ((size_t)b * Dc + m) * SKVc + 8 * g;

  // preload K fragments for iteration 0
  bf16x8 kf[4][2];
#pragma unroll
  for (int c = 0; c < 4; c++) {
    const bf16* kp = kb + (size_t)(16 * c + m) * Dc + 8 * g;
    kf[c][0] = *(const bf16x8*)kp;
    kf[c][1] = *(const bf16x8*)(kp + 32);
  }

  for (int it = 0; it < 32; ++it) {
    const int kt = it * 64;
    // ---- V loads for current iter (consumed after s=0's QK+exp2) ----
    bf16x8 vf[4][2];
#pragma unroll
    for (int t = 0; t < 4; t++) {
      const bf16* vp = vb + (size_t)(16 * t) * SKVc + kt;
      vf[t][0] = *(const bf16x8*)vp;
      vf[t][1] = *(const bf16x8*)(vp + 32);
    }
    // ---- K prefetch for next iter (full-iteration distance) ----
    bf16x8 kn[4][2];
    if (it + 1 < 32) {
#pragma unroll
      for (int c = 0; c < 4; c++) {
        const bf16* kp = kb + (size_t)(kt + 64 + 16 * c + m) * Dc + 8 * g;
        kn[c][0] = *(const bf16x8*)kp;
        kn[c][1] = *(const bf16x8*)(kp + 32);
      }
    }
    // ---- 4 independent s-blocks of 16 q-rows ----
#pragma unroll
    for (int s = 0; s < 4; s++) {
#pragma unroll
      for (int c = 0; c < 4; c++) {
        floatx4 sv = MFMA16(kf[c][0], bq[s][0], z);
        sv = MFMA16(kf[c][1], bq[s][1], sv);
        bf16x4 pk = {(bf16)EXP2F(sv[0]), (bf16)EXP2F(sv[1]), (bf16)EXP2F(sv[2]),
                     (bf16)EXP2F(sv[3])};
        *(bf16x4*)&Pb[wave][m][16 * c + 4 * g] = pk;
      }
      const bf16x8 pa0 = *(const bf16x8*)&Pb[wave][m][8 * g];
      const bf16x8 pa1 = *(const bf16x8*)&Pb[wave][m][32 + 8 * g];
      lacc[s] = MFMA16(pa0, ones, lacc[s]);
      lacc[s] = MFMA16(pa1, ones, lacc[s]);
#pragma unroll
      for (int t = 0; t < 4; t++) {
        accO[s][t] = MFMA16(pa0, vf[t][0], accO[s][t]);
        accO[s][t] = MFMA16(pa1, vf[t][1], accO[s][t]);
      }
    }
#pragma unroll
    for (int c = 0; c < 4; c++) {
      kf[c][0] = kn[c][0];
      kf[c][1] = kn[c][1];
    }
  }

  // ---- normalize and store h[b][s][h*64+d] ----
#pragma unroll
  for (int s = 0; s < 4; s++) {
    floatx4 inv;
#pragma unroll
    for (int r = 0; r < 4; r++) inv[r] = 1.0f / lacc[s][r];
#pragma unroll
    for (int t = 0; t < 4; t++)
#pragma unroll
      for (int r = 0; r < 4; r++) {
        const int qrow = q0 + 16 * s + 4 * g + r;
        hout[((size_t)(b * SQc + qrow)) * (Hc * Dc) + h * Dc + 16 * t + m] =
            (bf16)(accO[s][t][r] * inv[r]);
      }
  }
}

// ---------------------------------------------------------------------------
extern "C" void kernel_launch(void* const* d_in, const int* in_sizes, int n_in,
                              void* d_out, int out_size, void* d_ws, size_t ws_size,
                              hipStream_t stream) {
  const float* q = (const float*)d_in[0];
  const float* kv = (const float*)d_in[1];
  const float* Wq = (const float*)d_in[2];
  const float* bq = (const float*)d_in[3];
  const float* Wkv = (const float*)d_in[4];
  const float* bkv = (const float*)d_in[5];
  const float* Wo = (const float*)d_in[6];
  const float* bo = (const float*)d_in[7];

  char* ws = (char*)d_ws;
  bf16* qbf = (bf16*)ws;                            // 16 MiB (reused as hh later)
  bf16* kvbf = (bf16*)(ws + ((size_t)16 << 20));    // 16 MiB
  bf16* WqT = (bf16*)(ws + ((size_t)32 << 20));     // 2 MiB
  bf16* WkvT = (bf16*)(ws + ((size_t)34 << 20));    // 256 KiB
  bf16* WoT = (bf16*)(ws + ((size_t)35 << 20));     // 2 MiB
  bf16* qh = (bf16*)(ws + ((size_t)37 << 20));      // 16 MiB
  bf16* kk = (bf16*)(ws + ((size_t)53 << 20));      // 1 MiB
  bf16* vt = (bf16*)(ws + ((size_t)54 << 20));      // 1 MiB
  bf16* hh = qbf;  // alias: qbf dead after gemm1, hh written by attn

  const int M = Bc * SQc;  // 8192

  cvt_bf16<<<M, 256, 0, stream>>>(q, qbf);
  cvt_bf16<<<M, 256, 0, stream>>>(kv, kvbf);
  transpose_cvt<<<dim3(16, 16), 256, 0, stream>>>(Wq, WqT, 1024, 1024);
  transpose_cvt<<<dim3(2, 16), 256, 0, stream>>>(Wkv, WkvT, 1024, 128);
  transpose_cvt<<<dim3(16, 16), 256, 0, stream>>>(Wo, WoT, 1024, 1024);

  gemm_bf16<1><<<dim3(64, 8), 256, 0, stream>>>(qbf, WqT, bq, (void*)qh, nullptr,
                                                M, 1024, 1024);
  gemm_bf16<2><<<dim3(64, 1), 256, 0, stream>>>(kvbf, WkvT, bkv, (void*)kk,
                                                (void*)vt, M, 1024, 128);
  attn_v4<<<Bc * Hc * (SQc / 256), 256, 0, stream>>>(qh, kk, vt, hh);
  gemm_bf16<0><<<dim3(64, 8), 256, 0, stream>>>(hh, WoT, bo, d_out, nullptr, M,
                                                1024, 1024);
}

// Round 5
// 426.226 us; speedup vs baseline: 1.3804x; 1.0235x over previous
//
#include <hip/hip_runtime.h>
#include <math.h>

typedef __bf16 bf16;
typedef __bf16 bf16x4 __attribute__((ext_vector_type(4)));
typedef __bf16 bf16x8 __attribute__((ext_vector_type(8)));
typedef float floatx4 __attribute__((ext_vector_type(4)));

#define MFMA16(a, b, c) __builtin_amdgcn_mfma_f32_16x16x32_bf16(a, b, c, 0, 0, 0)

#if __has_builtin(__builtin_amdgcn_exp2f)
#define EXP2F(x) __builtin_amdgcn_exp2f(x)
#else
#define EXP2F(x) exp2f(x)
#endif

constexpr int Bc = 4, SQc = 2048, SKVc = 2048, Hc = 16, Dc = 64;
// fold 1/sqrt(D) * log2(e) into qh so softmax is exp2 with no extra mul
#define QSCALE 0.18033688011112042f

// Async global->LDS, 16B per lane. LDS dest is wave-uniform base + lane*16.
__device__ __forceinline__ void glds16(const bf16* g, bf16* lds_base, int lane) {
#if __has_builtin(__builtin_amdgcn_global_load_lds)
  __builtin_amdgcn_global_load_lds(
      (const __attribute__((address_space(1))) void*)g,
      (__attribute__((address_space(3))) void*)lds_base, 16, 0, 0);
#else
  *(bf16x8*)(lds_base + 8 * lane) = *(const bf16x8*)g;
#endif
}

// ---------------------------------------------------------------------------
// Prepass: fp32 -> bf16 convert (1024 elems per block)
// ---------------------------------------------------------------------------
__global__ void cvt_bf16(const float* __restrict__ in, bf16* __restrict__ out) {
  const size_t i = ((size_t)blockIdx.x * 256 + threadIdx.x) * 4;
  const float4 v = *(const float4*)&in[i];
  bf16x4 o = {(bf16)v.x, (bf16)v.y, (bf16)v.z, (bf16)v.w};
  *(bf16x4*)&out[i] = o;
}

// ---------------------------------------------------------------------------
// Prepass: W [K][N] fp32 -> WT [N][K] bf16. grid (N/64, K/64), 256 thr.
// ---------------------------------------------------------------------------
__global__ void transpose_cvt(const float* __restrict__ in, bf16* __restrict__ out,
                              int K, int N) {
  __shared__ bf16 T[64][72];
  const int tid = threadIdx.x;
  const int n0 = blockIdx.x * 64, k0 = blockIdx.y * 64;
  const int tr = tid >> 4, tc4 = (tid & 15) * 4;
#pragma unroll
  for (int i = 0; i < 4; i++) {
    const int k = tr + 16 * i;
    const float4 v = *(const float4*)&in[(size_t)(k0 + k) * N + n0 + tc4];
    T[tc4 + 0][k] = (bf16)v.x;
    T[tc4 + 1][k] = (bf16)v.y;
    T[tc4 + 2][k] = (bf16)v.z;
    T[tc4 + 3][k] = (bf16)v.w;
  }
  __syncthreads();
  const int nr = tid >> 2, kc = (tid & 3) * 8;
#pragma unroll
  for (int hf = 0; hf < 2; hf++)
    *(bf16x8*)&out[(size_t)(n0 + nr) * K + k0 + kc + 32 * hf] =
        *(const bf16x8*)&T[nr][kc + 32 * hf];
}

// ---------------------------------------------------------------------------
// Shared 128x128 / BK=64 K-loop body (global_load_lds staging, XOR swizzle).
// Computes acc[4][4] for tile (m0,n0) of C = A @ BT^T. K = 1024 fixed.
// ---------------------------------------------------------------------------
__device__ __forceinline__ void gemm_kloop(const bf16* __restrict__ A,
                                           const bf16* __restrict__ BT, int m0,
                                           int n0, int tid, int wave, int lane,
                                           int m, int g, bf16* As, bf16* Bs,
                                           floatx4 (*acc)[4], int mq, int nq) {
  for (int k0 = 0; k0 < 1024; k0 += 64) {
    __syncthreads();
#pragma unroll
    for (int q = 0; q < 4; q++) {
      const int G = q * 256 + tid;          // granule index 0..1023
      const int r = G >> 3, p = G & 7;      // row, physical granule
      const int s = p ^ (r & 7);            // source granule (swizzle)
      bf16* base = &As[(size_t)(q * 4 + wave) * 512];  // wave-uniform
      glds16(&A[(size_t)(m0 + r) * 1024 + k0 + 8 * s], base, lane);
      bf16* baseB = &Bs[(size_t)(q * 4 + wave) * 512];
      glds16(&BT[(size_t)(n0 + r) * 1024 + k0 + 8 * s], baseB, lane);
    }
    __syncthreads();  // drains vmcnt -> LDS tiles visible

    bf16x8 a[4][2], bb[4][2];
#pragma unroll
    for (int i = 0; i < 4; i++) {
      const int row = mq + 16 * i + m;
#pragma unroll
      for (int kh = 0; kh < 2; kh++)
        a[i][kh] = *(const bf16x8*)&As[row * 64 + 8 * ((g + 4 * kh) ^ (row & 7))];
    }
#pragma unroll
    for (int j = 0; j < 4; j++) {
      const int row = nq + 16 * j + m;
#pragma unroll
      for (int kh = 0; kh < 2; kh++)
        bb[j][kh] = *(const bf16x8*)&Bs[row * 64 + 8 * ((g + 4 * kh) ^ (row & 7))];
    }
#pragma unroll
    for (int i = 0; i < 4; i++)
#pragma unroll
      for (int j = 0; j < 4; j++) {
        acc[i][j] = MFMA16(a[i][0], bb[j][0], acc[i][j]);
        acc[i][j] = MFMA16(a[i][1], bb[j][1], acc[i][j]);
      }
  }
}

// ---------------------------------------------------------------------------
// Fused Q-proj + KV-proj. grid (64, 9): y<8 -> Q tiles (RoPE+QSCALE -> qh),
// y==8 -> KV tile (RoPE -> kk / transpose -> vt).
// ---------------------------------------------------------------------------
__global__ __launch_bounds__(256, 4) void gemm_qkv(
    const bf16* __restrict__ qA, const bf16* __restrict__ qBT,
    const float* __restrict__ qb, const bf16* __restrict__ kvA,
    const bf16* __restrict__ kvBT, const float* __restrict__ kvb,
    bf16* __restrict__ qh, bf16* __restrict__ kko, bf16* __restrict__ vto) {
  __shared__ bf16 As[128 * 64];
  __shared__ bf16 Bs[128 * 64];

  const int tid = threadIdx.x, lane = tid & 63, wave = tid >> 6;
  const int m = lane & 15, g = lane >> 4;
  const int m0 = blockIdx.x * 128;
  const bool isQ = (blockIdx.y < 8);
  const int n0 = isQ ? blockIdx.y * 128 : 0;
  const bf16* A = isQ ? qA : kvA;
  const bf16* BT = isQ ? qBT : kvBT;
  const float* bias = isQ ? qb : kvb;
  const int mq = (wave >> 1) * 64, nq = (wave & 1) * 64;

  floatx4 z = {0.f, 0.f, 0.f, 0.f};
  floatx4 acc[4][4];
#pragma unroll
  for (int i = 0; i < 4; i++)
#pragma unroll
    for (int j = 0; j < 4; j++) acc[i][j] = z;

  gemm_kloop(A, BT, m0, n0, tid, wave, lane, m, g, As, Bs, acc, mq, nq);

  const int rq = 4 * g;
#pragma unroll
  for (int j = 0; j < 4; j++) {
    const int col = n0 + nq + 16 * j + m;
    const float bv = bias[col];
#pragma unroll
    for (int i = 0; i < 4; i++) {
#pragma unroll
      for (int r = 0; r < 4; r++) {
        const int row = m0 + mq + 16 * i + rq + r;
        float v = acc[i][j][r] + bv;
        const float vp = __shfl_xor(v, 1);
        if (isQ) {
          const int d = col & 63, hh = col >> 6;
          const int pos = row & (SQc - 1), b = row >> 11;
          const float ang = (float)pos * exp2f(-0.375f * (float)(d >> 1));
          float sn, cs;
          sincosf(ang, &sn, &cs);
          const float res = (d & 1) ? (v * cs + vp * sn) : (v * cs - vp * sn);
          qh[(((size_t)(b * Hc + hh) * SQc) + pos) * Dc + d] = (bf16)(res * QSCALE);
        } else {
          const int pos = row & (SKVc - 1), b = row >> 11;
          if (col < 64) {  // wave-uniform (nq is 0 or 64)
            const int d = col;
            const float ang = (float)pos * exp2f(-0.375f * (float)(d >> 1));
            float sn, cs;
            sincosf(ang, &sn, &cs);
            const float res = (d & 1) ? (v * cs + vp * sn) : (v * cs - vp * sn);
            kko[((size_t)b * SKVc + pos) * Dc + d] = (bf16)res;
          } else {
            vto[((size_t)b * Dc + (col - 64)) * SKVc + pos] = (bf16)v;
          }
        }
      }
    }
  }
}

// ---------------------------------------------------------------------------
// O-projection: fp32 out. grid (64, 8).
// ---------------------------------------------------------------------------
__global__ __launch_bounds__(256, 4) void gemm_out(
    const bf16* __restrict__ A, const bf16* __restrict__ BT,
    const float* __restrict__ bias, float* __restrict__ out) {
  __shared__ bf16 As[128 * 64];
  __shared__ bf16 Bs[128 * 64];

  const int tid = threadIdx.x, lane = tid & 63, wave = tid >> 6;
  const int m = lane & 15, g = lane >> 4;
  const int m0 = blockIdx.x * 128, n0 = blockIdx.y * 128;
  const int mq = (wave >> 1) * 64, nq = (wave & 1) * 64;

  floatx4 z = {0.f, 0.f, 0.f, 0.f};
  floatx4 acc[4][4];
#pragma unroll
  for (int i = 0; i < 4; i++)
#pragma unroll
    for (int j = 0; j < 4; j++) acc[i][j] = z;

  gemm_kloop(A, BT, m0, n0, tid, wave, lane, m, g, As, Bs, acc, mq, nq);

  const int rq = 4 * g;
#pragma unroll
  for (int j = 0; j < 4; j++) {
    const int col = n0 + nq + 16 * j + m;
    const float bv = bias[col];
#pragma unroll
    for (int i = 0; i < 4; i++)
#pragma unroll
      for (int r = 0; r < 4; r++) {
        const int row = m0 + mq + 16 * i + rq + r;
        out[(size_t)row * 1024 + col] = acc[i][j][r] + bv;
      }
  }
}

// ---------------------------------------------------------------------------
// Flash attention v5: barrier-free, 64 q-rows per wave (4 s-blocks of 16).
// P relayout buffers PRIVATE per s-block -> no LDS aliasing between s-blocks,
// so the 4 chains (QK -> exp2 -> ds_write | ds_read -> PV) pipeline freely.
// K prefetched one iter ahead in registers; V loaded at iter top. Row-sums
// via MFMA against ones. Block = 256 q-rows. Grid = 512.
// ---------------------------------------------------------------------------
__global__ __launch_bounds__(256, 2) void attn_v5(
    const bf16* __restrict__ qh, const bf16* __restrict__ kk,
    const bf16* __restrict__ vt, bf16* __restrict__ hout) {
  const int bid = blockIdx.x;
  const int qt = bid & 7, h = (bid >> 3) & 15, b = bid >> 7;
  const int tid = threadIdx.x, lane = tid & 63, wave = tid >> 6;
  const int m = lane & 15, g = lane >> 4;

  __shared__ bf16 Pb[4][4][16][68];  // [wave][s-block][q][key] - private per s

  const int q0 = qt * 256 + wave * 64;
  // Q fragments (B-operand: n=q in lane&15, k=d)
  const bf16* qp = qh + (((size_t)(b * Hc + h) * SQc) + q0 + m) * Dc + 8 * g;
  bf16x8 bq[4][2];
#pragma unroll
  for (int s = 0; s < 4; s++) {
    bq[s][0] = *(const bf16x8*)(qp + (size_t)(16 * s) * Dc);
    bq[s][1] = *(const bf16x8*)(qp + (size_t)(16 * s) * Dc + 32);
  }

  const bf16 one = (bf16)1.0f;
  const bf16x8 ones = {one, one, one, one, one, one, one, one};

  floatx4 z = {0.f, 0.f, 0.f, 0.f};
  floatx4 accO[4][4];
  floatx4 lacc[4] = {z, z, z, z};
#pragma unroll
  for (int s = 0; s < 4; s++)
#pragma unroll
    for (int t = 0; t < 4; t++) accO[s][t] = z;

  const bf16* kb = kk + (size_t)b * SKVc * Dc;
  const bf16* vb = vt + ((size_t)b * Dc + m) * SKVc + 8 * g;

  // preload K fragments for iteration 0
  bf16x8 kf[4][2];
#pragma unroll
  for (int c = 0; c < 4; c++) {
    const bf16* kp = kb + (size_t)(16 * c + m) * Dc + 8 * g;
    kf[c][0] = *(const bf16x8*)kp;
    kf[c][1] = *(const bf16x8*)(kp + 32);
  }

  for (int it = 0; it < 32; ++it) {
    const int kt = it * 64;
    // ---- V loads for current iter (consumed in phase 2) ----
    bf16x8 vf[4][2];
#pragma unroll
    for (int t = 0; t < 4; t++) {
      const bf16* vp = vb + (size_t)(16 * t) * SKVc + kt;
      vf[t][0] = *(const bf16x8*)vp;
      vf[t][1] = *(const bf16x8*)(vp + 32);
    }
    // ---- K prefetch for next iter ----
    bf16x8 kn[4][2];
    if (it + 1 < 32) {
#pragma unroll
      for (int c = 0; c < 4; c++) {
        const bf16* kp = kb + (size_t)(kt + 64 + 16 * c + m) * Dc + 8 * g;
        kn[c][0] = *(const bf16x8*)kp;
        kn[c][1] = *(const bf16x8*)(kp + 32);
      }
    }
    // ---- phase 1: all s-blocks QK + exp2 + ds_write (independent buffers) --
#pragma unroll
    for (int s = 0; s < 4; s++) {
#pragma unroll
      for (int c = 0; c < 4; c++) {
        floatx4 sv = MFMA16(kf[c][0], bq[s][0], z);
        sv = MFMA16(kf[c][1], bq[s][1], sv);
        bf16x4 pk = {(bf16)EXP2F(sv[0]), (bf16)EXP2F(sv[1]), (bf16)EXP2F(sv[2]),
                     (bf16)EXP2F(sv[3])};
        *(bf16x4*)&Pb[wave][s][m][16 * c + 4 * g] = pk;
      }
    }
    // ---- phase 2: per s-block read P (A-layout) and accumulate PV ----
#pragma unroll
    for (int s = 0; s < 4; s++) {
      const bf16x8 pa0 = *(const bf16x8*)&Pb[wave][s][m][8 * g];
      const bf16x8 pa1 = *(const bf16x8*)&Pb[wave][s][m][32 + 8 * g];
      lacc[s] = MFMA16(pa0, ones, lacc[s]);
      lacc[s] = MFMA16(pa1, ones, lacc[s]);
#pragma unroll
      for (int t = 0; t < 4; t++) {
        accO[s][t] = MFMA16(pa0, vf[t][0], accO[s][t]);
        accO[s][t] = MFMA16(pa1, vf[t][1], accO[s][t]);
      }
    }
#pragma unroll
    for (int c = 0; c < 4; c++) {
      kf[c][0] = kn[c][0];
      kf[c][1] = kn[c][1];
    }
  }

  // ---- normalize and store h[b][s][h*64+d] ----
#pragma unroll
  for (int s = 0; s < 4; s++) {
    floatx4 inv;
#pragma unroll
    for (int r = 0; r < 4; r++) inv[r] = 1.0f / lacc[s][r];
#pragma unroll
    for (int t = 0; t < 4; t++)
#pragma unroll
      for (int r = 0; r < 4; r++) {
        const int qrow = q0 + 16 * s + 4 * g + r;
        hout[((size_t)(b * SQc + qrow)) * (Hc * Dc) + h * Dc + 16 * t + m] =
            (bf16)(accO[s][t][r] * inv[r]);
      }
  }
}

// ---------------------------------------------------------------------------
extern "C" void kernel_launch(void* const* d_in, const int* in_sizes, int n_in,
                              void* d_out, int out_size, void* d_ws, size_t ws_size,
                              hipStream_t stream) {
  const float* q = (const float*)d_in[0];
  const float* kv = (const float*)d_in[1];
  const float* Wq = (const float*)d_in[2];
  const float* bq = (const float*)d_in[3];
  const float* Wkv = (const float*)d_in[4];
  const float* bkv = (const float*)d_in[5];
  const float* Wo = (const float*)d_in[6];
  const float* bo = (const float*)d_in[7];

  char* ws = (char*)d_ws;
  bf16* qbf = (bf16*)ws;                            // 16 MiB (reused as hh later)
  bf16* kvbf = (bf16*)(ws + ((size_t)16 << 20));    // 16 MiB
  bf16* WqT = (bf16*)(ws + ((size_t)32 << 20));     // 2 MiB
  bf16* WkvT = (bf16*)(ws + ((size_t)34 << 20));    // 256 KiB
  bf16* WoT = (bf16*)(ws + ((size_t)35 << 20));     // 2 MiB
  bf16* qh = (bf16*)(ws + ((size_t)37 << 20));      // 16 MiB
  bf16* kk = (bf16*)(ws + ((size_t)53 << 20));      // 1 MiB
  bf16* vt = (bf16*)(ws + ((size_t)54 << 20));      // 1 MiB
  bf16* hh = qbf;  // alias: qbf dead after gemm_qkv, hh written by attn

  const int M = Bc * SQc;  // 8192

  cvt_bf16<<<M, 256, 0, stream>>>(q, qbf);
  cvt_bf16<<<M, 256, 0, stream>>>(kv, kvbf);
  transpose_cvt<<<dim3(16, 16), 256, 0, stream>>>(Wq, WqT, 1024, 1024);
  transpose_cvt<<<dim3(2, 16), 256, 0, stream>>>(Wkv, WkvT, 1024, 128);
  transpose_cvt<<<dim3(16, 16), 256, 0, stream>>>(Wo, WoT, 1024, 1024);

  gemm_qkv<<<dim3(64, 9), 256, 0, stream>>>(qbf, WqT, bq, kvbf, WkvT, bkv, qh, kk,
                                            vt);
  attn_v5<<<Bc * Hc * (SQc / 256), 256, 0, stream>>>(qh, kk, vt, hh);
  gemm_out<<<dim3(64, 8), 256, 0, stream>>>(hh, WoT, bo, (float*)d_out);
}

// Round 6
// 419.005 us; speedup vs baseline: 1.4042x; 1.0172x over previous
//
#include <hip/hip_runtime.h>
#include <math.h>

typedef __bf16 bf16;
typedef __bf16 bf16x4 __attribute__((ext_vector_type(4)));
typedef __bf16 bf16x8 __attribute__((ext_vector_type(8)));
typedef float floatx4 __attribute__((ext_vector_type(4)));

#define MFMA16(a, b, c) __builtin_amdgcn_mfma_f32_16x16x32_bf16(a, b, c, 0, 0, 0)

#if __has_builtin(__builtin_amdgcn_exp2f)
#define EXP2F(x) __builtin_amdgcn_exp2f(x)
#else
#define EXP2F(x) exp2f(x)
#endif

constexpr int Bc = 4, SQc = 2048, SKVc = 2048, Hc = 16, Dc = 64;
// fold 1/sqrt(D) * log2(e) into qh so softmax is exp2 with no extra mul
#define QSCALE 0.18033688011112042f

// Async global->LDS, 16B per lane. LDS dest is wave-uniform base + lane*16.
__device__ __forceinline__ void glds16(const bf16* g, bf16* lds_base, int lane) {
#if __has_builtin(__builtin_amdgcn_global_load_lds)
  __builtin_amdgcn_global_load_lds(
      (const __attribute__((address_space(1))) void*)g,
      (__attribute__((address_space(3))) void*)lds_base, 16, 0, 0);
#else
  *(bf16x8*)(lds_base + 8 * lane) = *(const bf16x8*)g;
#endif
}

// ---------------------------------------------------------------------------
// Prepass: fp32 -> bf16 convert (1024 elems per block)
// ---------------------------------------------------------------------------
__global__ void cvt_bf16(const float* __restrict__ in, bf16* __restrict__ out) {
  const size_t i = ((size_t)blockIdx.x * 256 + threadIdx.x) * 4;
  const float4 v = *(const float4*)&in[i];
  bf16x4 o = {(bf16)v.x, (bf16)v.y, (bf16)v.z, (bf16)v.w};
  *(bf16x4*)&out[i] = o;
}

// ---------------------------------------------------------------------------
// Prepass: W [K][N] fp32 -> WT [N][K] bf16. grid (N/64, K/64), 256 thr.
// ---------------------------------------------------------------------------
__global__ void transpose_cvt(const float* __restrict__ in, bf16* __restrict__ out,
                              int K, int N) {
  __shared__ bf16 T[64][72];
  const int tid = threadIdx.x;
  const int n0 = blockIdx.x * 64, k0 = blockIdx.y * 64;
  const int tr = tid >> 4, tc4 = (tid & 15) * 4;
#pragma unroll
  for (int i = 0; i < 4; i++) {
    const int k = tr + 16 * i;
    const float4 v = *(const float4*)&in[(size_t)(k0 + k) * N + n0 + tc4];
    T[tc4 + 0][k] = (bf16)v.x;
    T[tc4 + 1][k] = (bf16)v.y;
    T[tc4 + 2][k] = (bf16)v.z;
    T[tc4 + 3][k] = (bf16)v.w;
  }
  __syncthreads();
  const int nr = tid >> 2, kc = (tid & 3) * 8;
#pragma unroll
  for (int hf = 0; hf < 2; hf++)
    *(bf16x8*)&out[(size_t)(n0 + nr) * K + k0 + kc + 32 * hf] =
        *(const bf16x8*)&T[nr][kc + 32 * hf];
}

// ---------------------------------------------------------------------------
// Shared 128x128 / BK=64 K-loop body (global_load_lds staging, XOR swizzle).
// Register-pressure-aware: only the 4 B fragments are held across the MFMA
// loop; A fragments are loaded per-i. Staging pointers hoisted out of loop.
// ---------------------------------------------------------------------------
__device__ __forceinline__ void gemm_kloop(const bf16* __restrict__ A,
                                           const bf16* __restrict__ BT, int m0,
                                           int n0, int tid, int wave, int lane,
                                           int m, int g, bf16* As, bf16* Bs,
                                           floatx4 (*acc)[4], int mq, int nq) {
  // hoisted per-thread staging sources (advance by 64 elems per iter)
  const int r_ = tid >> 3, p_ = tid & 7;
  const int s_ = p_ ^ (r_ & 7);
  const bf16* pA[4];
  const bf16* pB[4];
#pragma unroll
  for (int q = 0; q < 4; q++) {
    const int r = r_ + q * 32;
    const int s = p_ ^ (r & 7);
    pA[q] = &A[(size_t)(m0 + r) * 1024 + 8 * s];
    pB[q] = &BT[(size_t)(n0 + r) * 1024 + 8 * s];
  }
  (void)s_;

  for (int k0 = 0; k0 < 1024; k0 += 64) {
    __syncthreads();
#pragma unroll
    for (int q = 0; q < 4; q++) {
      bf16* base = &As[(size_t)(q * 4 + wave) * 512];  // wave-uniform
      glds16(pA[q] + k0, base, lane);
      bf16* baseB = &Bs[(size_t)(q * 4 + wave) * 512];
      glds16(pB[q] + k0, baseB, lane);
    }
    __syncthreads();  // drains vmcnt -> LDS tiles visible

    bf16x8 bb[4][2];
#pragma unroll
    for (int j = 0; j < 4; j++) {
      const int row = nq + 16 * j + m;
#pragma unroll
      for (int kh = 0; kh < 2; kh++)
        bb[j][kh] = *(const bf16x8*)&Bs[row * 64 + 8 * ((g + 4 * kh) ^ (row & 7))];
    }
#pragma unroll
    for (int i = 0; i < 4; i++) {
      const int row = mq + 16 * i + m;
      const bf16x8 a0 = *(const bf16x8*)&As[row * 64 + 8 * (g ^ (row & 7))];
      const bf16x8 a1 = *(const bf16x8*)&As[row * 64 + 8 * ((g + 4) ^ (row & 7))];
#pragma unroll
      for (int j = 0; j < 4; j++) {
        acc[i][j] = MFMA16(a0, bb[j][0], acc[i][j]);
        acc[i][j] = MFMA16(a1, bb[j][1], acc[i][j]);
      }
    }
  }
}

// ---------------------------------------------------------------------------
// Fused Q-proj + KV-proj. grid (64, 9): y<8 -> Q tiles (RoPE+QSCALE -> qh),
// y==8 -> KV tile (RoPE -> kk / transpose -> vt).
// ---------------------------------------------------------------------------
__global__ __launch_bounds__(256, 3) void gemm_qkv(
    const bf16* __restrict__ qA, const bf16* __restrict__ qBT,
    const float* __restrict__ qb, const bf16* __restrict__ kvA,
    const bf16* __restrict__ kvBT, const float* __restrict__ kvb,
    bf16* __restrict__ qh, bf16* __restrict__ kko, bf16* __restrict__ vto) {
  __shared__ bf16 As[128 * 64];
  __shared__ bf16 Bs[128 * 64];

  const int tid = threadIdx.x, lane = tid & 63, wave = tid >> 6;
  const int m = lane & 15, g = lane >> 4;
  const int m0 = blockIdx.x * 128;
  const bool isQ = (blockIdx.y < 8);
  const int n0 = isQ ? blockIdx.y * 128 : 0;
  const bf16* A = isQ ? qA : kvA;
  const bf16* BT = isQ ? qBT : kvBT;
  const float* bias = isQ ? qb : kvb;
  const int mq = (wave >> 1) * 64, nq = (wave & 1) * 64;

  floatx4 z = {0.f, 0.f, 0.f, 0.f};
  floatx4 acc[4][4];
#pragma unroll
  for (int i = 0; i < 4; i++)
#pragma unroll
    for (int j = 0; j < 4; j++) acc[i][j] = z;

  gemm_kloop(A, BT, m0, n0, tid, wave, lane, m, g, As, Bs, acc, mq, nq);

  const int rq = 4 * g;
#pragma unroll
  for (int j = 0; j < 4; j++) {
    const int col = n0 + nq + 16 * j + m;
    const float bv = bias[col];
#pragma unroll
    for (int i = 0; i < 4; i++) {
#pragma unroll
      for (int r = 0; r < 4; r++) {
        const int row = m0 + mq + 16 * i + rq + r;
        float v = acc[i][j][r] + bv;
        const float vp = __shfl_xor(v, 1);
        if (isQ) {
          const int d = col & 63, hh = col >> 6;
          const int pos = row & (SQc - 1), b = row >> 11;
          const float ang = (float)pos * exp2f(-0.375f * (float)(d >> 1));
          float sn, cs;
          sincosf(ang, &sn, &cs);
          const float res = (d & 1) ? (v * cs + vp * sn) : (v * cs - vp * sn);
          qh[(((size_t)(b * Hc + hh) * SQc) + pos) * Dc + d] = (bf16)(res * QSCALE);
        } else {
          const int pos = row & (SKVc - 1), b = row >> 11;
          if (col < 64) {  // wave-uniform (nq is 0 or 64)
            const int d = col;
            const float ang = (float)pos * exp2f(-0.375f * (float)(d >> 1));
            float sn, cs;
            sincosf(ang, &sn, &cs);
            const float res = (d & 1) ? (v * cs + vp * sn) : (v * cs - vp * sn);
            kko[((size_t)b * SKVc + pos) * Dc + d] = (bf16)res;
          } else {
            vto[((size_t)b * Dc + (col - 64)) * SKVc + pos] = (bf16)v;
          }
        }
      }
    }
  }
}

// ---------------------------------------------------------------------------
// O-projection: fp32 out. grid (64, 8).
// ---------------------------------------------------------------------------
__global__ __launch_bounds__(256, 3) void gemm_out(
    const bf16* __restrict__ A, const bf16* __restrict__ BT,
    const float* __restrict__ bias, float* __restrict__ out) {
  __shared__ bf16 As[128 * 64];
  __shared__ bf16 Bs[128 * 64];

  const int tid = threadIdx.x, lane = tid & 63, wave = tid >> 6;
  const int m = lane & 15, g = lane >> 4;
  const int m0 = blockIdx.x * 128, n0 = blockIdx.y * 128;
  const int mq = (wave >> 1) * 64, nq = (wave & 1) * 64;

  floatx4 z = {0.f, 0.f, 0.f, 0.f};
  floatx4 acc[4][4];
#pragma unroll
  for (int i = 0; i < 4; i++)
#pragma unroll
    for (int j = 0; j < 4; j++) acc[i][j] = z;

  gemm_kloop(A, BT, m0, n0, tid, wave, lane, m, g, As, Bs, acc, mq, nq);

  const int rq = 4 * g;
#pragma unroll
  for (int j = 0; j < 4; j++) {
    const int col = n0 + nq + 16 * j + m;
    const float bv = bias[col];
#pragma unroll
    for (int i = 0; i < 4; i++)
#pragma unroll
      for (int r = 0; r < 4; r++) {
        const int row = m0 + mq + 16 * i + rq + r;
        out[(size_t)row * 1024 + col] = acc[i][j][r] + bv;
      }
  }
}

// ---------------------------------------------------------------------------
// Flash attention v5: barrier-free, 64 q-rows per wave (4 s-blocks of 16).
// P relayout buffers PRIVATE per s-block -> no LDS aliasing between s-blocks,
// so the 4 chains (QK -> exp2 -> ds_write | ds_read -> PV) pipeline freely.
// K prefetched one iter ahead in registers; V loaded at iter top. Row-sums
// via MFMA against ones. Block = 256 q-rows. Grid = 512.
// ---------------------------------------------------------------------------
__global__ __launch_bounds__(256, 2) void attn_v5(
    const bf16* __restrict__ qh, const bf16* __restrict__ kk,
    const bf16* __restrict__ vt, bf16* __restrict__ hout) {
  const int bid = blockIdx.x;
  const int qt = bid & 7, h = (bid >> 3) & 15, b = bid >> 7;
  const int tid = threadIdx.x, lane = tid & 63, wave = tid >> 6;
  const int m = lane & 15, g = lane >> 4;

  __shared__ bf16 Pb[4][4][16][68];  // [wave][s-block][q][key] - private per s

  const int q0 = qt * 256 + wave * 64;
  // Q fragments (B-operand: n=q in lane&15, k=d)
  const bf16* qp = qh + (((size_t)(b * Hc + h) * SQc) + q0 + m) * Dc + 8 * g;
  bf16x8 bq[4][2];
#pragma unroll
  for (int s = 0; s < 4; s++) {
    bq[s][0] = *(const bf16x8*)(qp + (size_t)(16 * s) * Dc);
    bq[s][1] = *(const bf16x8*)(qp + (size_t)(16 * s) * Dc + 32);
  }

  const bf16 one = (bf16)1.0f;
  const bf16x8 ones = {one, one, one, one, one, one, one, one};

  floatx4 z = {0.f, 0.f, 0.f, 0.f};
  floatx4 accO[4][4];
  floatx4 lacc[4] = {z, z, z, z};
#pragma unroll
  for (int s = 0; s < 4; s++)
#pragma unroll
    for (int t = 0; t < 4; t++) accO[s][t] = z;

  const bf16* kb = kk + (size_t)b * SKVc * Dc;
  const bf16* vb = vt + ((size_t)b * Dc + m) * SKVc + 8 * g;

  // preload K fragments for iteration 0
  bf16x8 kf[4][2];
#pragma unroll
  for (int c = 0; c < 4; c++) {
    const bf16* kp = kb + (size_t)(16 * c + m) * Dc + 8 * g;
    kf[c][0] = *(const bf16x8*)kp;
    kf[c][1] = *(const bf16x8*)(kp + 32);
  }

  for (int it = 0; it < 32; ++it) {
    const int kt = it * 64;
    // ---- V loads for current iter (consumed in phase 2) ----
    bf16x8 vf[4][2];
#pragma unroll
    for (int t = 0; t < 4; t++) {
      const bf16* vp = vb + (size_t)(16 * t) * SKVc + kt;
      vf[t][0] = *(const bf16x8*)vp;
      vf[t][1] = *(const bf16x8*)(vp + 32);
    }
    // ---- K prefetch for next iter ----
    bf16x8 kn[4][2];
    if (it + 1 < 32) {
#pragma unroll
      for (int c = 0; c < 4; c++) {
        const bf16* kp = kb + (size_t)(kt + 64 + 16 * c + m) * Dc + 8 * g;
        kn[c][0] = *(const bf16x8*)kp;
        kn[c][1] = *(const bf16x8*)(kp + 32);
      }
    }
    // ---- phase 1: all s-blocks QK + exp2 + ds_write (independent buffers) --
#pragma unroll
    for (int s = 0; s < 4; s++) {
#pragma unroll
      for (int c = 0; c < 4; c++) {
        floatx4 sv = MFMA16(kf[c][0], bq[s][0], z);
        sv = MFMA16(kf[c][1], bq[s][1], sv);
        bf16x4 pk = {(bf16)EXP2F(sv[0]), (bf16)EXP2F(sv[1]), (bf16)EXP2F(sv[2]),
                     (bf16)EXP2F(sv[3])};
        *(bf16x4*)&Pb[wave][s][m][16 * c + 4 * g] = pk;
      }
    }
    // ---- phase 2: per s-block read P (A-layout) and accumulate PV ----
#pragma unroll
    for (int s = 0; s < 4; s++) {
      const bf16x8 pa0 = *(const bf16x8*)&Pb[wave][s][m][8 * g];
      const bf16x8 pa1 = *(const bf16x8*)&Pb[wave][s][m][32 + 8 * g];
      lacc[s] = MFMA16(pa0, ones, lacc[s]);
      lacc[s] = MFMA16(pa1, ones, lacc[s]);
#pragma unroll
      for (int t = 0; t < 4; t++) {
        accO[s][t] = MFMA16(pa0, vf[t][0], accO[s][t]);
        accO[s][t] = MFMA16(pa1, vf[t][1], accO[s][t]);
      }
    }
#pragma unroll
    for (int c = 0; c < 4; c++) {
      kf[c][0] = kn[c][0];
      kf[c][1] = kn[c][1];
    }
  }

  // ---- normalize and store h[b][s][h*64+d] ----
#pragma unroll
  for (int s = 0; s < 4; s++) {
    floatx4 inv;
#pragma unroll
    for (int r = 0; r < 4; r++) inv[r] = 1.0f / lacc[s][r];
#pragma unroll
    for (int t = 0; t < 4; t++)
#pragma unroll
      for (int r = 0; r < 4; r++) {
        const int qrow = q0 + 16 * s + 4 * g + r;
        hout[((size_t)(b * SQc + qrow)) * (Hc * Dc) + h * Dc + 16 * t + m] =
            (bf16)(accO[s][t][r] * inv[r]);
      }
  }
}

// ---------------------------------------------------------------------------
extern "C" void kernel_launch(void* const* d_in, const int* in_sizes, int n_in,
                              void* d_out, int out_size, void* d_ws, size_t ws_size,
                              hipStream_t stream) {
  const float* q = (const float*)d_in[0];
  const float* kv = (const float*)d_in[1];
  const float* Wq = (const float*)d_in[2];
  const float* bq = (const float*)d_in[3];
  const float* Wkv = (const float*)d_in[4];
  const float* bkv = (const float*)d_in[5];
  const float* Wo = (const float*)d_in[6];
  const float* bo = (const float*)d_in[7];

  char* ws = (char*)d_ws;
  bf16* qbf = (bf16*)ws;                            // 16 MiB (reused as hh later)
  bf16* kvbf = (bf16*)(ws + ((size_t)16 << 20));    // 16 MiB
  bf16* WqT = (bf16*)(ws + ((size_t)32 << 20));     // 2 MiB
  bf16* WkvT = (bf16*)(ws + ((size_t)34 << 20));    // 256 KiB
  bf16* WoT = (bf16*)(ws + ((size_t)35 << 20));     // 2 MiB
  bf16* qh = (bf16*)(ws + ((size_t)37 << 20));      // 16 MiB
  bf16* kk = (bf16*)(ws + ((size_t)53 << 20));      // 1 MiB
  bf16* vt = (bf16*)(ws + ((size_t)54 << 20));      // 1 MiB
  bf16* hh = qbf;  // alias: qbf dead after gemm_qkv, hh written by attn

  const int M = Bc * SQc;  // 8192

  cvt_bf16<<<M, 256, 0, stream>>>(q, qbf);
  cvt_bf16<<<M, 256, 0, stream>>>(kv, kvbf);
  transpose_cvt<<<dim3(16, 16), 256, 0, stream>>>(Wq, WqT, 1024, 1024);
  transpose_cvt<<<dim3(2, 16), 256, 0, stream>>>(Wkv, WkvT, 1024, 128);
  transpose_cvt<<<dim3(16, 16), 256, 0, stream>>>(Wo, WoT, 1024, 1024);

  gemm_qkv<<<dim3(64, 9), 256, 0, stream>>>(qbf, WqT, bq, kvbf, WkvT, bkv, qh, kk,
                                            vt);
  attn_v5<<<Bc * Hc * (SQc / 256), 256, 0, stream>>>(qh, kk, vt, hh);
  gemm_out<<<dim3(64, 8), 256, 0, stream>>>(hh, WoT, bo, (float*)d_out);
}